// Round 1
// 136.213 us; speedup vs baseline: 1.0719x; 1.0719x over previous
//
#include <hip/hip_runtime.h>
#include <hip/hip_bf16.h>
#include <math.h>

#define BATCH 16
#define LEN   160000
#define NFFT  512
#define HOP   128
#define NT    1251      // 1 + (160000+512-512)/128
#define NF    257
#define PADC  256
#define TWO_PI 6.28318530717958647692f
// padded LDS index: +1 float per 32 -> breaks power-of-2 bank aliasing
#define P(i) ((i) + ((i) >> 5))
#define FBUF 528        // padded 512-float FFT region (P(511)=526 < 528)
#define GSTR 264        // staging row stride: 2 rows == FBUF exactly

__device__ __forceinline__ int reflect_idx(int j) {
    j = j < 0 ? -j : j;
    j = j >= LEN ? 2*LEN - 2 - j : j;
    return j;
}

__device__ __forceinline__ float hann(int n) {
    return 0.5f - 0.5f * __cosf(TWO_PI * (float)n * (1.0f / 512.0f));
}

__device__ __forceinline__ __hip_bfloat162 pack_bf2(float x, float y) {
    __hip_bfloat162 r; r.x = __float2bfloat16(x); r.y = __float2bfloat16(y); return r;
}
__device__ __forceinline__ float2 unpack_bf2(__hip_bfloat162 v) {
    return make_float2(__bfloat162float(v.x), __bfloat162float(v.y));
}

// ---------- sorted-4-smallest tuple machinery (exact, branchless) ----------
struct T4 { float m0, m1, m2, m3; };   // ascending

__device__ __forceinline__ void ins(T4& a, float v) {
    const float x0 = fminf(a.m0, v);  const float c0 = fmaxf(a.m0, v);
    const float x1 = fminf(a.m1, c0); const float c1 = fmaxf(a.m1, c0);
    const float x2 = fminf(a.m2, c1); const float c2 = fmaxf(a.m2, c1);
    const float x3 = fminf(a.m3, c2);
    a.m0 = x0; a.m1 = x1; a.m2 = x2; a.m3 = x3;
}

__device__ __forceinline__ T4 merge4(const T4& a, const T4& b) {
    const float l0 = fminf(a.m0, b.m3);
    const float l1 = fminf(a.m1, b.m2);
    const float l2 = fminf(a.m2, b.m1);
    const float l3 = fminf(a.m3, b.m0);
    const float t0 = fminf(l0, l2), t2 = fmaxf(l0, l2);
    const float t1 = fminf(l1, l3), t3 = fmaxf(l1, l3);
    T4 r;
    r.m0 = fminf(t0, t1); r.m1 = fmaxf(t0, t1);
    r.m2 = fminf(t2, t3); r.m3 = fmaxf(t2, t3);
    return r;
}

__device__ __forceinline__ T4 sort4(float a, float b, float c, float d) {
    const float x0 = fminf(a, b), x1 = fmaxf(a, b);
    const float x2 = fminf(c, d), x3 = fmaxf(c, d);
    const float y0 = fminf(x0, x2), y2 = fmaxf(x0, x2);
    const float y1 = fminf(x1, x3), y3 = fmaxf(x1, x3);
    T4 r; r.m0 = y0; r.m1 = fminf(y1, y2); r.m2 = fmaxf(y1, y2); r.m3 = y3;
    return r;
}

// 8-point DFT in registers. y[m] = sum_r v[r] * exp(sign*2*pi*i*r*m/8).
__device__ __forceinline__ void dft8(float vr[8], float vi[8], float sign) {
    const float K = 0.70710678118654752f;
    float ar=vr[0]+vr[4], ai=vi[0]+vi[4];
    float br=vr[0]-vr[4], bi=vi[0]-vi[4];
    float cr=vr[2]+vr[6], ci=vi[2]+vi[6];
    float dr=vr[2]-vr[6], di=vi[2]-vi[6];
    float er=vr[1]+vr[5], ei=vi[1]+vi[5];
    float fr=vr[1]-vr[5], fi=vi[1]-vi[5];
    float gr=vr[3]+vr[7], gi=vi[3]+vi[7];
    float hr=vr[3]-vr[7], hi=vi[3]-vi[7];
    const float W4dr = -sign*di, W4di = sign*dr;
    const float W4hr = -sign*hi, W4hi = sign*hr;
    const float E0r=ar+cr, E0i=ai+ci, E2r=ar-cr, E2i=ai-ci;
    const float E1r=br+W4dr, E1i=bi+W4di, E3r=br-W4dr, E3i=bi-W4di;
    const float O0r=er+gr, O0i=ei+gi, O2r=er-gr, O2i=ei-gi;
    const float O1r=fr+W4hr, O1i=fi+W4hi, O3r=fr-W4hr, O3i=fi-W4hi;
    const float T1r = K*(O1r - sign*O1i), T1i = K*(O1i + sign*O1r);
    const float T2r = -sign*O2i,          T2i = sign*O2r;
    const float T3r = K*(-O3r - sign*O3i), T3i = K*(-O3i + sign*O3r);
    vr[0]=E0r+O0r; vi[0]=E0i+O0i;  vr[4]=E0r-O0r; vi[4]=E0i-O0i;
    vr[1]=E1r+T1r; vi[1]=E1i+T1i;  vr[5]=E1r-T1r; vi[5]=E1i-T1i;
    vr[2]=E2r+T2r; vi[2]=E2i+T2i;  vr[6]=E2r-T2r; vi[6]=E2i-T2i;
    vr[3]=E3r+T3r; vi[3]=E3i+T3i;  vr[7]=E3r-T3r; vi[7]=E3i-T3i;
}

// One Stockham radix-8 pass, IN PLACE, one wave = one FFT (j in 0..63).
// Barrier-free: all ds_reads precede all ds_writes in program order.
template<int NS>
__device__ __forceinline__ void fft_pass(float* R, float* I, int j, float sign) {
    float vr[8], vi[8];
    #pragma unroll
    for (int r = 0; r < 8; ++r) { vr[r] = R[P(j + 64*r)]; vi[r] = I[P(j + 64*r)]; }
    const float th = sign * (TWO_PI / (8.0f * (float)NS)) * (float)(j & (NS - 1));
    float w1r, w1i; __sincosf(th, &w1i, &w1r);
    float wr = w1r, wi = w1i;
    #pragma unroll
    for (int r = 1; r < 8; ++r) {
        const float tr = vr[r]*wr - vi[r]*wi;
        vi[r] = vr[r]*wi + vi[r]*wr; vr[r] = tr;
        const float nwr = wr*w1r - wi*w1i;
        wi = wr*w1i + wi*w1r; wr = nwr;
    }
    dft8(vr, vi, sign);
    const int base = ((j / NS) * (8 * NS)) + (j & (NS - 1));
    #pragma unroll
    for (int r = 0; r < 8; ++r) { R[P(base + r*NS)] = vr[r]; I[P(base + r*NS)] = vi[r]; }
}

// Final pass (NS=64): results stay in REGISTERS. After this, lane j holds
// y[j + 64r] in vr[r]/vi[r]. No LDS write.
__device__ __forceinline__ void fft_pass_last(const float* R, const float* I, int j,
                                              float sign, float vr[8], float vi[8]) {
    #pragma unroll
    for (int r = 0; r < 8; ++r) { vr[r] = R[P(j + 64*r)]; vi[r] = I[P(j + 64*r)]; }
    const float th = sign * (TWO_PI / 512.0f) * (float)j;
    float w1r, w1i; __sincosf(th, &w1i, &w1r);
    float wr = w1r, wi = w1i;
    #pragma unroll
    for (int r = 1; r < 8; ++r) {
        const float tr = vr[r]*wr - vi[r]*wi;
        vi[r] = vr[r]*wi + vi[r]*wr; vr[r] = tr;
        const float nwr = wr*w1r - wi*w1i;
        wi = wr*w1i + wi*w1r; wr = nwr;
    }
    dft8(vr, vi, sign);
}

// K1: STFT of BOTH signals via one complex FFT per frame: z = enh + i*noi.
// 4 frames per block (one per wave), wave-autonomous in-place radix-8
// Stockham, ZERO __syncthreads. Last pass in registers; Hermitian partner
// via __shfl. Outputs stored as BF16.
// ALSO zeroes the OLA output buffer (replaces the separate hipMemsetAsync
// dispatch): 313 blocks * 256 thr * 2 floats = 160256 >= LEN per batch.
__global__ __launch_bounds__(256, 6) void stft_kernel(const float* __restrict__ enh,
                                                      const float* __restrict__ noi,
                                                      __hip_bfloat162* __restrict__ e_spec,
                                                      __hip_bfloat16*  __restrict__ n_mag,
                                                      float* __restrict__ out) {
    __shared__ float Ar[4*FBUF], Ai[4*FBUF];
    const int tid = threadIdx.x;
    const int w = tid >> 6, j = tid & 63;
    const int tr_ = blockIdx.x * 4 + w;
    const bool live = tr_ < NT;
    const int t = live ? tr_ : NT - 1;
    const int b = blockIdx.y;
    float* ar = Ar + w*FBUF; float* ai = Ai + w*FBUF;

    // zero the output slice (fire-and-forget stores; K3 waits on this kernel)
    {
        const int z = (blockIdx.x << 9) + (tid << 1);
        if (z < LEN) *reinterpret_cast<float2*>(out + (size_t)b * LEN + z) = make_float2(0.0f, 0.0f);
    }

    // pass 0: global -> registers (windowed), dft8, write A
    {
        const int sbase = t * HOP - PADC;
        float vr[8], vi[8];
        if (sbase >= 0 && sbase + NFFT <= LEN) {
            const float* __restrict__ pe = enh + b * LEN + sbase;
            const float* __restrict__ pn = noi + b * LEN + sbase;
            #pragma unroll
            for (int r = 0; r < 8; ++r) {
                const int n = j + 64*r;
                const float wd = hann(n);
                vr[r] = pe[n] * wd;
                vi[r] = pn[n] * wd;
            }
        } else {
            const float* __restrict__ pe = enh + b * LEN;
            const float* __restrict__ pn = noi + b * LEN;
            #pragma unroll
            for (int r = 0; r < 8; ++r) {
                const int n = j + 64*r;
                const int idx = reflect_idx(sbase + n);
                const float wd = hann(n);
                vr[r] = pe[idx] * wd;
                vi[r] = pn[idx] * wd;
            }
        }
        dft8(vr, vi, -1.0f);
        #pragma unroll
        for (int r = 0; r < 8; ++r) { ar[P(8*j + r)] = vr[r]; ai[P(8*j + r)] = vi[r]; }
    }
    fft_pass<8>(ar, ai, j, -1.0f);
    float zr[8], zi[8];
    fft_pass_last(ar, ai, j, -1.0f, zr, zi);

    // Hermitian partner via cross-lane shuffle (regs 4..7 of lane (64-j)&63)
    const int src = (64 - j) & 63;
    float pr[4], pi_[4];
    #pragma unroll
    for (int q = 4; q < 8; ++q) {
        pr[q-4]  = __shfl(zr[q], src);
        pi_[q-4] = __shfl(zi[q], src);
    }
    if (live) {
        const int obase = (b * NT + t) * NF;
        #pragma unroll
        for (int r = 0; r < 4; ++r) {
            const int kk = j + 64*r;
            const float yr = (j == 0) ? zr[(8 - r) & 7] : pr[3 - r];
            const float yi = (j == 0) ? zi[(8 - r) & 7] : pi_[3 - r];
            const float er = 0.5f*(zr[r] + yr), ei = 0.5f*(zi[r] - yi);
            const float nr = 0.5f*(zi[r] + yi), ni = 0.5f*(yr - zr[r]);
            e_spec[obase + kk] = pack_bf2(er, ei);
            n_mag[obase + kk] = __float2bfloat16(fmaxf(sqrtf(nr*nr + ni*ni), 1e-6f));
        }
        if (j == 0) {   // kk = 256: self-conjugate bin
            e_spec[obase + 256] = pack_bf2(zr[4], 0.0f);
            n_mag[obase + 256] = __float2bfloat16(fmaxf(fabsf(zi[4]), 1e-6f));
        }
    }
}

// K3 (FUSED): [rolling-quantile floor + pools + mask + ISTFT + OLA] in one
// kernel. Per block of 8 frames: recompute the 16 quantile rows this tile
// needs (tq = t0-4 .. t0+11) directly from n_mag (46-element time window,
// 5 sorted chunks + 7 singles -> exact 4th-smallest of 31), freq-pool k=5
// via LDS, time-pool k=9 in registers, sigmoid mask, then the existing
// wave-autonomous inverse FFT + OLA. The q[16][GSTR] tile (16.9 KB)
// exactly aliases the gr/gi staging planes (8+8 rows), so LDS = 16.9 KB.
// Eliminates: floor_ global array (41 MB round-trip), K2 dispatch+tail.
// (256,4): VGPR cap 128 covers the wv[46]+ch[5] high-water (~85) w/o spill.
__global__ __launch_bounds__(256, 4) void floor_mask_istft_kernel(
        const __hip_bfloat162* __restrict__ g,
        const __hip_bfloat16* __restrict__ n_mag,
        float* __restrict__ out) {
    __shared__ float smem[16 * GSTR];   // q[16][GSTR]  UNION  gr[8*GSTR]+gi[8*GSTR]
    __shared__ float fq[16];
    float (*q)[GSTR] = reinterpret_cast<float (*)[GSTR]>(smem);
    float* gr = smem;
    float* gi = smem + 8 * GSTR;

    const int tid = threadIdx.x;
    const int w = tid >> 6, j = tid & 63;
    const int t0 = blockIdx.x * 8, b = blockIdx.y;
    const __hip_bfloat16* __restrict__ pb = n_mag + b * NT * NF;

    // ---- phase Q: quantile rows k=0..15 (tq = t0-4+k) for f = tid ----
    {
        float wv[46];
        #pragma unroll
        for (int r = 0; r < 46; ++r) {
            int tr = t0 - 19 + r;
            tr = tr < 0 ? 0 : (tr > NT - 1 ? NT - 1 : tr);
            wv[r] = __bfloat162float(pb[tr * NF + tid]);
        }
        T4 ch[5];
        #pragma unroll
        for (int c = 0; c < 5; ++c)
            ch[c] = merge4(sort4(wv[8*c],   wv[8*c+1], wv[8*c+2], wv[8*c+3]),
                           sort4(wv[8*c+4], wv[8*c+5], wv[8*c+6], wv[8*c+7]));
        #pragma unroll
        for (int k = 0; k < 16; ++k) {
            const int c0 = (k + 7) >> 3;      // full chunks c0, c0+1, c0+2
            T4 m = merge4(merge4(ch[c0], ch[c0+1]), ch[c0+2]);
            #pragma unroll
            for (int jj = k; jj < 8*c0; ++jj) ins(m, wv[jj]);           // head
            #pragma unroll
            for (int jj = 8*c0 + 24; jj < k + 31; ++jj) ins(m, wv[jj]); // tail
            q[k][tid] = m.m3;
        }
    }
    if (tid < 16) {   // f = 256 column: one quantile row each (naive 31-insert)
        const int k = tid;
        T4 m; m.m0 = m.m1 = m.m2 = m.m3 = 3.4e38f;
        for (int dt = -15; dt <= 15; ++dt) {
            int tt = t0 - 4 + k + dt;
            tt = tt < 0 ? 0 : (tt > NT - 1 ? NT - 1 : tt);
            ins(m, __bfloat162float(pb[tt * NF + 256]));
        }
        q[k][256] = m.m3;
    }
    __syncthreads();

    // ---- phase B: freq pool k=5 (zero-pad) into registers; fq for f=256 ----
    float fp[16];
    {
        const int f = tid;
        #pragma unroll
        for (int k = 0; k < 16; ++k) {
            float acc = 0.0f;
            #pragma unroll
            for (int df = -2; df <= 2; ++df) {
                const int ff = f + df;
                if (ff >= 0 && ff < NF) acc += q[k][ff];
            }
            fp[k] = acc * (1.0f / 5.0f);
        }
    }
    if (tid < 16) fq[tid] = (q[tid][254] + q[tid][255] + q[tid][256]) * (1.0f / 5.0f);
    __syncthreads();   // all q reads complete before gr/gi overwrite; fq visible

    // ---- phase C: zero out-of-range rows, time pool k=9 -> floor in regs ----
    float flv[8];
    {
        #pragma unroll
        for (int k = 0; k < 16; ++k) {
            const int tq = t0 - 4 + k;
            fp[k] = (tq >= 0 && tq < NT) ? fp[k] : 0.0f;
        }
        float acc = 0.0f;
        #pragma unroll
        for (int k = 0; k < 9; ++k) acc += fp[k];
        #pragma unroll
        for (int to = 0; to < 8; ++to) {
            flv[to] = fmaxf(acc * (1.0f / 9.0f), 1e-6f);
            if (to < 7) acc += fp[to + 9] - fp[to];
        }
    }

    // ---- phase D: mask -> staging rows gr/gi (overwrites the q region) ----
    {
        const int f = tid;
        #pragma unroll
        for (int ft = 0; ft < 8; ++ft) {
            const int t = t0 + ft;
            float grv = 0.0f, giv = 0.0f;
            if (t < NT) {
                const float fl = flv[ft];
                const float2 e2 = unpack_bf2(g[(b * NT + t) * NF + f]);
                const float a = sqrtf(e2.x * e2.x + e2.y * e2.y);
                const float emag = fmaxf(a, 1e-6f);
                const float xarg = (emag - 1.5f * fl) / (0.15f * fl + 1e-6f);
                const float mask = 1.0f / (1.0f + __expf(-xarg));
                const float fm = 0.08f + 0.92f * (0.65f + 0.35f * mask);
                const float scale = emag * fm / fmaxf(a, 1e-12f);
                grv = e2.x * scale; giv = e2.y * scale;
            }
            gr[ft * GSTR + f] = grv;
            gi[ft * GSTR + f] = giv;
        }
    }
    if (tid < 8) {   // f = 256 column of each frame
        const int ft = tid;
        const int t = t0 + ft;
        float grv = 0.0f, giv = 0.0f;
        if (t < NT) {
            float acc = 0.0f;
            #pragma unroll
            for (int k = 0; k < 9; ++k) {
                const int tq = t0 - 4 + ft + k;
                acc += (tq >= 0 && tq < NT) ? fq[ft + k] : 0.0f;
            }
            const float fl = fmaxf(acc * (1.0f / 9.0f), 1e-6f);
            const float2 e2 = unpack_bf2(g[(b * NT + t) * NF + 256]);
            const float a = sqrtf(e2.x * e2.x + e2.y * e2.y);
            const float emag = fmaxf(a, 1e-6f);
            const float xarg = (emag - 1.5f * fl) / (0.15f * fl + 1e-6f);
            const float mask = 1.0f / (1.0f + __expf(-xarg));
            const float fm = 0.08f + 0.92f * (0.65f + 0.35f * mask);
            const float scale = emag * fm / fmaxf(a, 1e-12f);
            grv = e2.x * scale; giv = e2.y * scale;
        }
        gr[ft * GSTR + 256] = grv;
        gi[ft * GSTR + 256] = giv;
    }
    __syncthreads();   // staging rows written by all threads; FFT reads cross-wave

    // ---- inverse FFT: wave w handles frames ta = t0+2w, t0+2w+1 packed ----
    float* g0r = gr + (2*w) * GSTR;      float* g0i = gi + (2*w) * GSTR;
    float* g1r = gr + (2*w + 1) * GSTR;  float* g1i = gi + (2*w + 1) * GSTR;
    float* ar = g0r;   // FFT region = this wave's two staging rows (528 floats)
    float* ai = g0i;

    // pass 0: build packed C(n) = G1full + i*G2full from staging, dft8,
    // write back into the same region (all reads precede all writes).
    {
        float vr[8], vi[8];
        #pragma unroll
        for (int r = 0; r < 8; ++r) {
            const int n = j + 64*r;
            float cr, ci;
            if (n <= 256) {
                cr = g0r[n] - g1i[n];
                ci = g0i[n] + g1r[n];
            } else {
                const int m = 512 - n;
                cr = g0r[m] + g1i[m];
                ci = g1r[m] - g0i[m];
            }
            vr[r] = cr; vi[r] = ci;
        }
        dft8(vr, vi, 1.0f);
        #pragma unroll
        for (int r = 0; r < 8; ++r) { ar[P(8*j + r)] = vr[r]; ai[P(8*j + r)] = vi[r]; }
    }
    fft_pass<8>(ar, ai, j, 1.0f);
    float xr[8], xi[8];
    fft_pass_last(ar, ai, j, 1.0f, xr, xi);

    // window in place: Re plane = frame ta, Im plane = frame ta+1
    #pragma unroll
    for (int r = 0; r < 8; ++r) {
        const int n = j + 64*r;
        const float wd = hann(n) * (1.0f / 512.0f);
        ar[P(n)] = xr[r] * wd;
        ai[P(n)] = xi[r] * wd;
    }
    __syncthreads();

    // OLA: samples i in [t0*128, t0*128 + 1408) (padded coords)
    const int i0 = t0 << 7;
    for (int s = tid; s < 1408; s += 256) {
        const int i = i0 + s;
        const int jj = i - PADC;
        if (jj < 0 || jj >= LEN) continue;
        const int tl = (i >= 384) ? ((i - 384) >> 7) : 0;
        int th = i >> 7; if (th > NT - 1) th = NT - 1;
        const int ca = tl > t0 ? tl : t0;             // this block's frame range
        const int cb = th < t0 + 7 ? th : t0 + 7;
        if (cb < ca) continue;
        float acc = 0.0f;
        for (int t = ca; t <= cb; ++t) {
            const int ft = t - t0;
            const int n = i - (t << 7);
            acc += ((ft & 1) ? gi : gr)[(ft >> 1) * FBUF + P(n)];
        }
        float winv;
        if (th - tl == 3) winv = (2.0f / 3.0f);       // COLA: sum hann^2 = 1.5
        else {
            float wacc = 0.0f;
            for (int t = tl; t <= th; ++t) {
                const float wd = hann(i - (t << 7));
                wacc += wd * wd;
            }
            winv = 1.0f / fmaxf(wacc, 1e-11f);
        }
        const float v = acc * winv;
        if (tl >= t0 && th <= t0 + 7) out[b * LEN + jj] = v;        // unique owner
        else atomicAdd(out + b * LEN + jj, v);                      // boundary partial
    }
}

extern "C" void kernel_launch(void* const* d_in, const int* in_sizes, int n_in,
                              void* d_out, int out_size, void* d_ws, size_t ws_size,
                              hipStream_t stream) {
    const float* noisy    = (const float*)d_in[0];
    const float* enhanced = (const float*)d_in[1];
    float* out = (float*)d_out;

    // workspace layout (float offsets), total ~31 MB:
    //   e_spec : [0, 5144112)               (16*1251*257 bf16x2 = 4B each)
    //   n_mag  : [5144112, 6430140)         (bf16, 2B each)
    float* ws = (float*)d_ws;
    __hip_bfloat162* e_spec = (__hip_bfloat162*)ws;
    __hip_bfloat16* n_mag = (__hip_bfloat16*)(ws + 5144112);

    stft_kernel<<<dim3((NT + 3) / 4, BATCH), dim3(256), 0, stream>>>(enhanced, noisy, e_spec, n_mag, out);
    floor_mask_istft_kernel<<<dim3((NT + 7) / 8, BATCH), dim3(256), 0, stream>>>(e_spec, n_mag, out);
}

// Round 2
// 128.662 us; speedup vs baseline: 1.1348x; 1.0587x over previous
//
#include <hip/hip_runtime.h>
#include <hip/hip_bf16.h>
#include <math.h>

#define BATCH 16
#define LEN   160000
#define NFFT  512
#define HOP   128
#define NT    1251      // 1 + (160000+512-512)/128
#define NF    257
#define PADC  256
#define TWO_PI 6.28318530717958647692f
// padded LDS index: +1 float per 32 -> breaks power-of-2 bank aliasing
#define P(i) ((i) + ((i) >> 5))
#define FBUF 528        // padded 512-float FFT region (P(511)=526 < 528)
#define GSTR 264        // staging row stride: 2 rows == FBUF exactly

__device__ __forceinline__ int reflect_idx(int j) {
    j = j < 0 ? -j : j;
    j = j >= LEN ? 2*LEN - 2 - j : j;
    return j;
}

__device__ __forceinline__ float hann(int n) {
    return 0.5f - 0.5f * __cosf(TWO_PI * (float)n * (1.0f / 512.0f));
}

__device__ __forceinline__ __hip_bfloat162 pack_bf2(float x, float y) {
    __hip_bfloat162 r; r.x = __float2bfloat16(x); r.y = __float2bfloat16(y); return r;
}
__device__ __forceinline__ float2 unpack_bf2(__hip_bfloat162 v) {
    return make_float2(__bfloat162float(v.x), __bfloat162float(v.y));
}

// ---------- sorted-4-smallest tuple machinery (exact, branchless) ----------
struct T4 { float m0, m1, m2, m3; };   // ascending

__device__ __forceinline__ void ins(T4& a, float v) {
    const float x0 = fminf(a.m0, v);  const float c0 = fmaxf(a.m0, v);
    const float x1 = fminf(a.m1, c0); const float c1 = fmaxf(a.m1, c0);
    const float x2 = fminf(a.m2, c1); const float c2 = fmaxf(a.m2, c1);
    const float x3 = fminf(a.m3, c2);
    a.m0 = x0; a.m1 = x1; a.m2 = x2; a.m3 = x3;
}

__device__ __forceinline__ T4 sort4(float a, float b, float c, float d) {
    const float x0 = fminf(a, b), x1 = fmaxf(a, b);
    const float x2 = fminf(c, d), x3 = fmaxf(c, d);
    const float y0 = fminf(x0, x2), y2 = fmaxf(x0, x2);
    const float y1 = fminf(x1, x3), y3 = fmaxf(x1, x3);
    T4 r; r.m0 = y0; r.m1 = fminf(y1, y2); r.m2 = fmaxf(y1, y2); r.m3 = y3;
    return r;
}

// 4th-smallest of union(a, b) where both are ascending 4-smallest tuples.
// m3 of the full merge = max of the four cross mins. 7 ops.
__device__ __forceinline__ float merge4_m3(const T4& a, const T4& b) {
    const float l0 = fminf(a.m0, b.m3);
    const float l1 = fminf(a.m1, b.m2);
    const float l2 = fminf(a.m2, b.m1);
    const float l3 = fminf(a.m3, b.m0);
    return fmaxf(fmaxf(l0, l1), fmaxf(l2, l3));
}

// 8-point DFT in registers. y[m] = sum_r v[r] * exp(sign*2*pi*i*r*m/8).
__device__ __forceinline__ void dft8(float vr[8], float vi[8], float sign) {
    const float K = 0.70710678118654752f;
    float ar=vr[0]+vr[4], ai=vi[0]+vi[4];
    float br=vr[0]-vr[4], bi=vi[0]-vi[4];
    float cr=vr[2]+vr[6], ci=vi[2]+vi[6];
    float dr=vr[2]-vr[6], di=vi[2]-vi[6];
    float er=vr[1]+vr[5], ei=vi[1]+vi[5];
    float fr=vr[1]-vr[5], fi=vi[1]-vi[5];
    float gr=vr[3]+vr[7], gi=vi[3]+vi[7];
    float hr=vr[3]-vr[7], hi=vi[3]-vi[7];
    const float W4dr = -sign*di, W4di = sign*dr;
    const float W4hr = -sign*hi, W4hi = sign*hr;
    const float E0r=ar+cr, E0i=ai+ci, E2r=ar-cr, E2i=ai-ci;
    const float E1r=br+W4dr, E1i=bi+W4di, E3r=br-W4dr, E3i=bi-W4di;
    const float O0r=er+gr, O0i=ei+gi, O2r=er-gr, O2i=ei-gi;
    const float O1r=fr+W4hr, O1i=fi+W4hi, O3r=fr-W4hr, O3i=fi-W4hi;
    const float T1r = K*(O1r - sign*O1i), T1i = K*(O1i + sign*O1r);
    const float T2r = -sign*O2i,          T2i = sign*O2r;
    const float T3r = K*(-O3r - sign*O3i), T3i = K*(-O3i + sign*O3r);
    vr[0]=E0r+O0r; vi[0]=E0i+O0i;  vr[4]=E0r-O0r; vi[4]=E0i-O0i;
    vr[1]=E1r+T1r; vi[1]=E1i+T1i;  vr[5]=E1r-T1r; vi[5]=E1i-T1i;
    vr[2]=E2r+T2r; vi[2]=E2i+T2i;  vr[6]=E2r-T2r; vi[6]=E2i-T2i;
    vr[3]=E3r+T3r; vi[3]=E3i+T3i;  vr[7]=E3r-T3r; vi[7]=E3i-T3i;
}

// One Stockham radix-8 pass, IN PLACE, one wave = one FFT (j in 0..63).
// Barrier-free: all ds_reads precede all ds_writes in program order.
template<int NS>
__device__ __forceinline__ void fft_pass(float* R, float* I, int j, float sign) {
    float vr[8], vi[8];
    #pragma unroll
    for (int r = 0; r < 8; ++r) { vr[r] = R[P(j + 64*r)]; vi[r] = I[P(j + 64*r)]; }
    const float th = sign * (TWO_PI / (8.0f * (float)NS)) * (float)(j & (NS - 1));
    float w1r, w1i; __sincosf(th, &w1i, &w1r);
    float wr = w1r, wi = w1i;
    #pragma unroll
    for (int r = 1; r < 8; ++r) {
        const float tr = vr[r]*wr - vi[r]*wi;
        vi[r] = vr[r]*wi + vi[r]*wr; vr[r] = tr;
        const float nwr = wr*w1r - wi*w1i;
        wi = wr*w1i + wi*w1r; wr = nwr;
    }
    dft8(vr, vi, sign);
    const int base = ((j / NS) * (8 * NS)) + (j & (NS - 1));
    #pragma unroll
    for (int r = 0; r < 8; ++r) { R[P(base + r*NS)] = vr[r]; I[P(base + r*NS)] = vi[r]; }
}

// Final pass (NS=64): results stay in REGISTERS. After this, lane j holds
// y[j + 64r] in vr[r]/vi[r]. No LDS write.
__device__ __forceinline__ void fft_pass_last(const float* R, const float* I, int j,
                                              float sign, float vr[8], float vi[8]) {
    #pragma unroll
    for (int r = 0; r < 8; ++r) { vr[r] = R[P(j + 64*r)]; vi[r] = I[P(j + 64*r)]; }
    const float th = sign * (TWO_PI / 512.0f) * (float)j;
    float w1r, w1i; __sincosf(th, &w1i, &w1r);
    float wr = w1r, wi = w1i;
    #pragma unroll
    for (int r = 1; r < 8; ++r) {
        const float tr = vr[r]*wr - vi[r]*wi;
        vi[r] = vr[r]*wi + vi[r]*wr; vr[r] = tr;
        const float nwr = wr*w1r - wi*w1i;
        wi = wr*w1i + wi*w1r; wr = nwr;
    }
    dft8(vr, vi, sign);
}

// K1: STFT of BOTH signals via one complex FFT per frame: z = enh + i*noi.
// 4 frames per block (one per wave), wave-autonomous in-place radix-8
// Stockham, ZERO __syncthreads. Last pass in registers; Hermitian partner
// via __shfl. Outputs stored as BF16.
// ALSO zeroes the OLA output buffer (replaces the separate hipMemsetAsync
// dispatch): 313 blocks * 256 thr * 2 floats = 160256 >= LEN per batch.
__global__ __launch_bounds__(256, 6) void stft_kernel(const float* __restrict__ enh,
                                                      const float* __restrict__ noi,
                                                      __hip_bfloat162* __restrict__ e_spec,
                                                      __hip_bfloat16*  __restrict__ n_mag,
                                                      float* __restrict__ out) {
    __shared__ float Ar[4*FBUF], Ai[4*FBUF];
    const int tid = threadIdx.x;
    const int w = tid >> 6, j = tid & 63;
    const int tr_ = blockIdx.x * 4 + w;
    const bool live = tr_ < NT;
    const int t = live ? tr_ : NT - 1;
    const int b = blockIdx.y;
    float* ar = Ar + w*FBUF; float* ai = Ai + w*FBUF;

    // zero the output slice (fire-and-forget stores; K3 waits on this kernel)
    {
        const int z = (blockIdx.x << 9) + (tid << 1);
        if (z < LEN) *reinterpret_cast<float2*>(out + (size_t)b * LEN + z) = make_float2(0.0f, 0.0f);
    }

    // pass 0: global -> registers (windowed), dft8, write A
    {
        const int sbase = t * HOP - PADC;
        float vr[8], vi[8];
        if (sbase >= 0 && sbase + NFFT <= LEN) {
            const float* __restrict__ pe = enh + b * LEN + sbase;
            const float* __restrict__ pn = noi + b * LEN + sbase;
            #pragma unroll
            for (int r = 0; r < 8; ++r) {
                const int n = j + 64*r;
                const float wd = hann(n);
                vr[r] = pe[n] * wd;
                vi[r] = pn[n] * wd;
            }
        } else {
            const float* __restrict__ pe = enh + b * LEN;
            const float* __restrict__ pn = noi + b * LEN;
            #pragma unroll
            for (int r = 0; r < 8; ++r) {
                const int n = j + 64*r;
                const int idx = reflect_idx(sbase + n);
                const float wd = hann(n);
                vr[r] = pe[idx] * wd;
                vi[r] = pn[idx] * wd;
            }
        }
        dft8(vr, vi, -1.0f);
        #pragma unroll
        for (int r = 0; r < 8; ++r) { ar[P(8*j + r)] = vr[r]; ai[P(8*j + r)] = vi[r]; }
    }
    fft_pass<8>(ar, ai, j, -1.0f);
    float zr[8], zi[8];
    fft_pass_last(ar, ai, j, -1.0f, zr, zi);

    // Hermitian partner via cross-lane shuffle (regs 4..7 of lane (64-j)&63)
    const int src = (64 - j) & 63;
    float pr[4], pi_[4];
    #pragma unroll
    for (int q = 4; q < 8; ++q) {
        pr[q-4]  = __shfl(zr[q], src);
        pi_[q-4] = __shfl(zi[q], src);
    }
    if (live) {
        const int obase = (b * NT + t) * NF;
        #pragma unroll
        for (int r = 0; r < 4; ++r) {
            const int kk = j + 64*r;
            const float yr = (j == 0) ? zr[(8 - r) & 7] : pr[3 - r];
            const float yi = (j == 0) ? zi[(8 - r) & 7] : pi_[3 - r];
            const float er = 0.5f*(zr[r] + yr), ei = 0.5f*(zi[r] - yi);
            const float nr = 0.5f*(zi[r] + yi), ni = 0.5f*(yr - zr[r]);
            e_spec[obase + kk] = pack_bf2(er, ei);
            n_mag[obase + kk] = __float2bfloat16(fmaxf(sqrtf(nr*nr + ni*ni), 1e-6f));
        }
        if (j == 0) {   // kk = 256: self-conjugate bin
            e_spec[obase + 256] = pack_bf2(zr[4], 0.0f);
            n_mag[obase + 256] = __float2bfloat16(fmaxf(fabsf(zi[4]), 1e-6f));
        }
    }
}

// K3 (FUSED): [rolling-quantile floor + pools + mask + ISTFT + OLA].
// Quantile now via van Herk / two-stacks sliding selection: all 16 windows
// [k, k+31) contain split point 16, so
//   suffix chain s[k] = 4-smallest of wv[k..16)      (15 ins)
//   one streaming prefix chain over wv[16..46)       (sort4 + 26 ins)
//   q[k] = m3 of merge(s[k], prefix_after(k+30))     (7-op merge-m3)
// ~430 fmin/fmax per thread vs ~1300 for the chunked network. Exact same
// 4th-smallest element -> bit-identical output.
__global__ __launch_bounds__(256, 4) void floor_mask_istft_kernel(
        const __hip_bfloat162* __restrict__ g,
        const __hip_bfloat16* __restrict__ n_mag,
        float* __restrict__ out) {
    __shared__ float smem[16 * GSTR];   // q[16][GSTR]  UNION  gr[8*GSTR]+gi[8*GSTR]
    __shared__ float fq[16];
    float (*q)[GSTR] = reinterpret_cast<float (*)[GSTR]>(smem);
    float* gr = smem;
    float* gi = smem + 8 * GSTR;

    const int tid = threadIdx.x;
    const int w = tid >> 6, j = tid & 63;
    const int t0 = blockIdx.x * 8, b = blockIdx.y;
    const __hip_bfloat16* __restrict__ pb = n_mag + b * NT * NF;

    // ---- phase Q: quantile rows k=0..15 (tq = t0-4+k) for f = tid ----
    {
        const int f = tid;
        // batch 1: rows 0..15 of the 46-row span (tr = t0-19 .. t0-4)
        float wa[16];
        #pragma unroll
        for (int r = 0; r < 16; ++r) {
            int tr = t0 - 19 + r;
            tr = tr < 0 ? 0 : (tr > NT - 1 ? NT - 1 : tr);
            wa[r] = __bfloat162float(pb[tr * NF + f]);
        }
        // suffix chain: s[k] = 4-smallest T4 of wa[k..16)
        T4 s[16];
        s[15].m0 = wa[15]; s[15].m1 = 3.4e38f; s[15].m2 = 3.4e38f; s[15].m3 = 3.4e38f;
        #pragma unroll
        for (int k = 14; k >= 0; --k) { s[k] = s[k+1]; ins(s[k], wa[k]); }
        // batch 2: rows 16..30 -> prefix chain seed (15 elements)
        float wc[15];
        #pragma unroll
        for (int r = 0; r < 15; ++r) {
            int tr = t0 - 3 + r;
            tr = tr < 0 ? 0 : (tr > NT - 1 ? NT - 1 : tr);
            wc[r] = __bfloat162float(pb[tr * NF + f]);
        }
        T4 p = sort4(wc[0], wc[1], wc[2], wc[3]);
        #pragma unroll
        for (int r = 4; r < 15; ++r) ins(p, wc[r]);
        // batch 3: rows 31..45 streamed into the prefix chain
        float wb[15];
        #pragma unroll
        for (int r = 0; r < 15; ++r) {
            int tr = t0 + 12 + r;
            tr = tr < 0 ? 0 : (tr > NT - 1 ? NT - 1 : tr);
            wb[r] = __bfloat162float(pb[tr * NF + f]);
        }
        #pragma unroll
        for (int k = 0; k < 16; ++k) {
            q[k][f] = merge4_m3(s[k], p);
            if (k < 15) ins(p, wb[k]);
        }
    }
    if (tid < 16) {   // f = 256 column: one quantile row each (naive 31-insert)
        const int k = tid;
        T4 m; m.m0 = m.m1 = m.m2 = m.m3 = 3.4e38f;
        for (int dt = -15; dt <= 15; ++dt) {
            int tt = t0 - 4 + k + dt;
            tt = tt < 0 ? 0 : (tt > NT - 1 ? NT - 1 : tt);
            ins(m, __bfloat162float(pb[tt * NF + 256]));
        }
        q[k][256] = m.m3;
    }
    __syncthreads();

    // ---- phase B: freq pool k=5 (zero-pad) into registers; fq for f=256 ----
    float fp[16];
    {
        const int f = tid;
        #pragma unroll
        for (int k = 0; k < 16; ++k) {
            float acc = 0.0f;
            #pragma unroll
            for (int df = -2; df <= 2; ++df) {
                const int ff = f + df;
                if (ff >= 0 && ff < NF) acc += q[k][ff];
            }
            fp[k] = acc * (1.0f / 5.0f);
        }
    }
    if (tid < 16) fq[tid] = (q[tid][254] + q[tid][255] + q[tid][256]) * (1.0f / 5.0f);
    __syncthreads();   // all q reads complete before gr/gi overwrite; fq visible

    // ---- phase C: zero out-of-range rows, time pool k=9 -> floor in regs ----
    float flv[8];
    {
        #pragma unroll
        for (int k = 0; k < 16; ++k) {
            const int tq = t0 - 4 + k;
            fp[k] = (tq >= 0 && tq < NT) ? fp[k] : 0.0f;
        }
        float acc = 0.0f;
        #pragma unroll
        for (int k = 0; k < 9; ++k) acc += fp[k];
        #pragma unroll
        for (int to = 0; to < 8; ++to) {
            flv[to] = fmaxf(acc * (1.0f / 9.0f), 1e-6f);
            if (to < 7) acc += fp[to + 9] - fp[to];
        }
    }

    // ---- phase D: mask -> staging rows gr/gi (overwrites the q region) ----
    {
        const int f = tid;
        #pragma unroll
        for (int ft = 0; ft < 8; ++ft) {
            const int t = t0 + ft;
            float grv = 0.0f, giv = 0.0f;
            if (t < NT) {
                const float fl = flv[ft];
                const float2 e2 = unpack_bf2(g[(b * NT + t) * NF + f]);
                const float a = sqrtf(e2.x * e2.x + e2.y * e2.y);
                const float emag = fmaxf(a, 1e-6f);
                const float xarg = (emag - 1.5f * fl) / (0.15f * fl + 1e-6f);
                const float mask = 1.0f / (1.0f + __expf(-xarg));
                const float fm = 0.08f + 0.92f * (0.65f + 0.35f * mask);
                const float scale = emag * fm / fmaxf(a, 1e-12f);
                grv = e2.x * scale; giv = e2.y * scale;
            }
            gr[ft * GSTR + f] = grv;
            gi[ft * GSTR + f] = giv;
        }
    }
    if (tid < 8) {   // f = 256 column of each frame
        const int ft = tid;
        const int t = t0 + ft;
        float grv = 0.0f, giv = 0.0f;
        if (t < NT) {
            float acc = 0.0f;
            #pragma unroll
            for (int k = 0; k < 9; ++k) {
                const int tq = t0 - 4 + ft + k;
                acc += (tq >= 0 && tq < NT) ? fq[ft + k] : 0.0f;
            }
            const float fl = fmaxf(acc * (1.0f / 9.0f), 1e-6f);
            const float2 e2 = unpack_bf2(g[(b * NT + t) * NF + 256]);
            const float a = sqrtf(e2.x * e2.x + e2.y * e2.y);
            const float emag = fmaxf(a, 1e-6f);
            const float xarg = (emag - 1.5f * fl) / (0.15f * fl + 1e-6f);
            const float mask = 1.0f / (1.0f + __expf(-xarg));
            const float fm = 0.08f + 0.92f * (0.65f + 0.35f * mask);
            const float scale = emag * fm / fmaxf(a, 1e-12f);
            grv = e2.x * scale; giv = e2.y * scale;
        }
        gr[ft * GSTR + 256] = grv;
        gi[ft * GSTR + 256] = giv;
    }
    __syncthreads();   // staging rows written by all threads; FFT reads cross-wave

    // ---- inverse FFT: wave w handles frames ta = t0+2w, t0+2w+1 packed ----
    float* g0r = gr + (2*w) * GSTR;      float* g0i = gi + (2*w) * GSTR;
    float* g1r = gr + (2*w + 1) * GSTR;  float* g1i = gi + (2*w + 1) * GSTR;
    float* ar = g0r;   // FFT region = this wave's two staging rows (528 floats)
    float* ai = g0i;

    // pass 0: build packed C(n) = G1full + i*G2full from staging, dft8,
    // write back into the same region (all reads precede all writes).
    {
        float vr[8], vi[8];
        #pragma unroll
        for (int r = 0; r < 8; ++r) {
            const int n = j + 64*r;
            float cr, ci;
            if (n <= 256) {
                cr = g0r[n] - g1i[n];
                ci = g0i[n] + g1r[n];
            } else {
                const int m = 512 - n;
                cr = g0r[m] + g1i[m];
                ci = g1r[m] - g0i[m];
            }
            vr[r] = cr; vi[r] = ci;
        }
        dft8(vr, vi, 1.0f);
        #pragma unroll
        for (int r = 0; r < 8; ++r) { ar[P(8*j + r)] = vr[r]; ai[P(8*j + r)] = vi[r]; }
    }
    fft_pass<8>(ar, ai, j, 1.0f);
    float xr[8], xi[8];
    fft_pass_last(ar, ai, j, 1.0f, xr, xi);

    // window in place: Re plane = frame ta, Im plane = frame ta+1
    #pragma unroll
    for (int r = 0; r < 8; ++r) {
        const int n = j + 64*r;
        const float wd = hann(n) * (1.0f / 512.0f);
        ar[P(n)] = xr[r] * wd;
        ai[P(n)] = xi[r] * wd;
    }
    __syncthreads();

    // OLA: samples i in [t0*128, t0*128 + 1408) (padded coords)
    const int i0 = t0 << 7;
    for (int s = tid; s < 1408; s += 256) {
        const int i = i0 + s;
        const int jj = i - PADC;
        if (jj < 0 || jj >= LEN) continue;
        const int tl = (i >= 384) ? ((i - 384) >> 7) : 0;
        int th = i >> 7; if (th > NT - 1) th = NT - 1;
        const int ca = tl > t0 ? tl : t0;             // this block's frame range
        const int cb = th < t0 + 7 ? th : t0 + 7;
        if (cb < ca) continue;
        float acc = 0.0f;
        for (int t = ca; t <= cb; ++t) {
            const int ft = t - t0;
            const int n = i - (t << 7);
            acc += ((ft & 1) ? gi : gr)[(ft >> 1) * FBUF + P(n)];
        }
        float winv;
        if (th - tl == 3) winv = (2.0f / 3.0f);       // COLA: sum hann^2 = 1.5
        else {
            float wacc = 0.0f;
            for (int t = tl; t <= th; ++t) {
                const float wd = hann(i - (t << 7));
                wacc += wd * wd;
            }
            winv = 1.0f / fmaxf(wacc, 1e-11f);
        }
        const float v = acc * winv;
        if (tl >= t0 && th <= t0 + 7) out[b * LEN + jj] = v;        // unique owner
        else atomicAdd(out + b * LEN + jj, v);                      // boundary partial
    }
}

extern "C" void kernel_launch(void* const* d_in, const int* in_sizes, int n_in,
                              void* d_out, int out_size, void* d_ws, size_t ws_size,
                              hipStream_t stream) {
    const float* noisy    = (const float*)d_in[0];
    const float* enhanced = (const float*)d_in[1];
    float* out = (float*)d_out;

    // workspace layout (float offsets), total ~31 MB:
    //   e_spec : [0, 5144112)               (16*1251*257 bf16x2 = 4B each)
    //   n_mag  : [5144112, 6430140)         (bf16, 2B each)
    float* ws = (float*)d_ws;
    __hip_bfloat162* e_spec = (__hip_bfloat162*)ws;
    __hip_bfloat16* n_mag = (__hip_bfloat16*)(ws + 5144112);

    stft_kernel<<<dim3((NT + 3) / 4, BATCH), dim3(256), 0, stream>>>(enhanced, noisy, e_spec, n_mag, out);
    floor_mask_istft_kernel<<<dim3((NT + 7) / 8, BATCH), dim3(256), 0, stream>>>(e_spec, n_mag, out);
}